// Round 9
// baseline (197.247 us; speedup 1.0000x reference)
//
#include <hip/hip_runtime.h>
#include <hip/hip_fp16.h>

#define N_NODES 50000
#define N_EDGES 800000
#define D_IN 128
#define HH 4
#define FF 16
#define HF 64  // HH*FF
#define NBUCKETS 196                 // ceil(N_NODES/256); bucket b covers dst in [b*256, b*256+256)
#define BCAP 4608                    // bucket capacity; Poisson(4096) + 8 sigma
#define CHUNK 1024                   // edges per bin_kernel block
#define NBIN_BLOCKS ((N_EDGES + CHUNK - 1) / CHUNK)  // 782
#define NBLK_SCAN ((N_NODES + 255) / 256)            // 196
#define GEMM_BLOCKS ((N_NODES + 63) / 64)            // 782

struct __align__(8) Half4 { __half2 a, b; };

typedef _Float16 half2_v __attribute__((ext_vector_type(2)));
struct __align__(8) H4 { half2_v a, b; };

__device__ __forceinline__ float dot4h(H4 a, H4 v) {
#if __has_builtin(__builtin_amdgcn_fdot2)
    return __builtin_amdgcn_fdot2(a.a, v.a,
           __builtin_amdgcn_fdot2(a.b, v.b, 0.0f, false), false);
#else
    return (float)a.a[0] * (float)v.a[0] + (float)a.a[1] * (float)v.a[1]
         + (float)a.b[0] * (float)v.b[0] + (float)a.b[1] * (float)v.b[1];
#endif
}

// ---------------- GEMM: ft[N,64] = feat[N,128] @ W[128,64], fp16 output ----------------
__global__ __launch_bounds__(256, 2) void gemm_kernel(const float* __restrict__ feat,
                                                      const float* __restrict__ W,
                                                      __half* __restrict__ fth) {
    __shared__ float As[64][132];   // padded: row stride 132 breaks 4-way bank conflict
    __shared__ float Bs[D_IN][HF];

    {
        const float4* W4 = (const float4*)W;
        float4* B4 = (float4*)Bs;
#pragma unroll
        for (int i = 0; i < 8; ++i) {
            int idx = threadIdx.x + 256 * i;
            B4[idx] = W4[idx];
        }
    }
    {
        int row0 = blockIdx.x * 64;
        const float4* F4 = (const float4*)feat;
#pragma unroll
        for (int i = 0; i < 8; ++i) {
            int idx = threadIdx.x + 256 * i;
            int r = idx >> 5;
            int c4 = idx & 31;
            float4 v = make_float4(0.f, 0.f, 0.f, 0.f);
            int row = row0 + r;
            if (row < N_NODES) v = F4[(size_t)row * 32 + c4];
            *(float4*)&As[r][c4 * 4] = v;
        }
    }
    __syncthreads();

    const int tr = threadIdx.x >> 4;
    const int tc = threadIdx.x & 15;

    float acc[4][4] = {};
#pragma unroll 8
    for (int k = 0; k < D_IN; k += 4) {
        float av[4][4], bv[4][4];
#pragma unroll
        for (int i = 0; i < 4; ++i) {
            float4 a = *(const float4*)&As[tr * 4 + i][k];
            av[i][0] = a.x; av[i][1] = a.y; av[i][2] = a.z; av[i][3] = a.w;
        }
#pragma unroll
        for (int j = 0; j < 4; ++j) {
            float4 b = *(const float4*)&Bs[k + j][tc * 4];
            bv[j][0] = b.x; bv[j][1] = b.y; bv[j][2] = b.z; bv[j][3] = b.w;
        }
#pragma unroll
        for (int i = 0; i < 4; ++i)
#pragma unroll
            for (int j = 0; j < 4; ++j)
#pragma unroll
                for (int c = 0; c < 4; ++c)
                    acc[i][c] = fmaf(av[i][j], bv[j][c], acc[i][c]);
    }

    int row0 = blockIdx.x * 64;
#pragma unroll
    for (int i = 0; i < 4; ++i) {
        int row = row0 + tr * 4 + i;
        if (row < N_NODES) {
            Half4 h;
            h.a = __floats2half2_rn(acc[i][0], acc[i][1]);
            h.b = __floats2half2_rn(acc[i][2], acc[i][3]);
            *(Half4*)&fth[(size_t)row * HF + tc * 4] = h;
        }
    }
}

// ---------------- pass 1: bin edges into 196 dst-buckets + per-node degree ----------------
// rec = src(16b) | (dst&255)<<16 | bucket<<24. LDS counting sort per block,
// fully block-parallel flush. Also accumulates the per-node degree histogram
// (global atomics, L2-resident counters).
__global__ __launch_bounds__(256) void bin_kernel(const int* __restrict__ src,
                                                  const int* __restrict__ dst,
                                                  int* __restrict__ gcur,
                                                  int* __restrict__ recs,
                                                  int* __restrict__ deg) {
    __shared__ int hist[256];
    __shared__ int offs[256];
    __shared__ int cur[256];
    __shared__ int gbase[256];
    __shared__ int lrec[CHUNK];

    int tid = threadIdx.x;
    int e0 = blockIdx.x * CHUNK;
    int n = N_EDGES - e0; if (n > CHUNK) n = CHUNK;

    hist[tid] = 0;
    __syncthreads();

    int myrec[CHUNK / 256];
    int myb[CHUNK / 256];
#pragma unroll
    for (int k = 0; k < CHUNK / 256; ++k) {
        int idx = tid + k * 256;
        myb[k] = -1;
        if (idx < n) {
            int s = src[e0 + idx];
            int d = dst[e0 + idx];
            int b = d >> 8;
            myrec[k] = s | ((d & 255) << 16) | (b << 24);
            myb[k] = b;
            atomicAdd(&hist[b], 1);
            atomicAdd(&deg[d], 1);
        }
    }
    __syncthreads();

    // exclusive scan of hist (Hillis-Steele over 256)
    int val = hist[tid];
    offs[tid] = val;
    __syncthreads();
#pragma unroll
    for (int off = 1; off < 256; off <<= 1) {
        int t = (tid >= off) ? offs[tid - off] : 0;
        __syncthreads();
        offs[tid] += t;
        __syncthreads();
    }
    int excl = offs[tid] - val;
    __syncthreads();
    offs[tid] = excl;
    cur[tid] = excl;
    if (tid < NBUCKETS && val > 0) gbase[tid] = atomicAdd(&gcur[tid], val);
    __syncthreads();

#pragma unroll
    for (int k = 0; k < CHUNK / 256; ++k) {
        if (myb[k] >= 0) {
            int p = atomicAdd(&cur[myb[k]], 1);
            lrec[p] = myrec[k];
        }
    }
    __syncthreads();

    // parallel flush: bucket id is in the record
    for (int i = tid; i < n; i += 256) {
        int r = lrec[i];
        int b = (r >> 24) & 255;
        int pos = gbase[b] + (i - offs[b]);
        if (pos < BCAP) recs[(size_t)b * BCAP + pos] = r;
    }
}

// ---------------- scan stage 1: per-256-block exclusive scan of deg ----------------
__global__ __launch_bounds__(256) void scan1_kernel(const int* __restrict__ deg,
                                                    int* __restrict__ row_ptr,
                                                    int* __restrict__ block_sums) {
    __shared__ int s[256];
    int tid = threadIdx.x;
    int i = blockIdx.x * 256 + tid;
    int val = (i < N_NODES) ? deg[i] : 0;
    s[tid] = val;
    __syncthreads();
#pragma unroll
    for (int off = 1; off < 256; off <<= 1) {
        int t = (tid >= off) ? s[tid - off] : 0;
        __syncthreads();
        s[tid] += t;
        __syncthreads();
    }
    if (i < N_NODES) row_ptr[i] = s[tid] - val;  // exclusive
    if (tid == 255) block_sums[blockIdx.x] = s[255];
}

// ---------------- scan stage 2: scan the 196 block sums ----------------
__global__ __launch_bounds__(256) void scan2_kernel(int* __restrict__ block_sums) {
    __shared__ int s[256];
    int tid = threadIdx.x;
    int val = (tid < NBLK_SCAN) ? block_sums[tid] : 0;
    s[tid] = val;
    __syncthreads();
#pragma unroll
    for (int off = 1; off < 256; off <<= 1) {
        int t = (tid >= off) ? s[tid - off] : 0;
        __syncthreads();
        s[tid] += t;
        __syncthreads();
    }
    if (tid < NBLK_SCAN) block_sums[tid] = s[tid] - val;  // exclusive
}

// ---------------- scan stage 3: add block offsets; init cursor ----------------
__global__ __launch_bounds__(256) void scan3_kernel(int* __restrict__ row_ptr,
                                                    const int* __restrict__ block_sums,
                                                    int* __restrict__ cursor) {
    int tid = threadIdx.x;
    int i = blockIdx.x * 256 + tid;
    if (i < N_NODES) {
        int v = row_ptr[i] + block_sums[blockIdx.x];
        row_ptr[i] = v;
        cursor[i] = v;
    }
    if (blockIdx.x == 0 && tid == 0) row_ptr[N_NODES] = N_EDGES;
}

// ---------------- scatter: bucketed recs -> globally contiguous CSR ----------------
// 4 blocks per bucket. Writes land within the bucket's ~16 KB csr window ->
// lines fill densely; cursor atomics are L2-resident.
__global__ __launch_bounds__(256) void scatter_kernel(const int* __restrict__ gcur,
                                                      const int* __restrict__ recs,
                                                      int* __restrict__ cursor,
                                                      int* __restrict__ csr) {
    int j = blockIdx.x;
    int b = j >> 2;
    int q = j & 3;
    int cnt = gcur[b]; if (cnt > BCAP) cnt = BCAP;
    int lo = q * (BCAP / 4);
    int hi = lo + (BCAP / 4); if (hi > cnt) hi = cnt;
    const int* rp = recs + (size_t)b * BCAP;
    for (int i = lo + threadIdx.x; i < hi; i += 256) {
        int rec = rp[i];
        int node = (b << 8) + ((rec >> 16) & 255);
        int p = atomicAdd(&cursor[node], 1);
        csr[p] = rec & 0xFFFF;
    }
}

// ---------------- fused gather: one wave per node, FOUR edges per load ----------------
// lane = g*16 + hl: g = edge slot (0..3), hl = feature-quad (features 4hl..4hl+3
// as half4). 16 lanes cover a full 64-feature row -> one global_load_dwordx2
// fetches 4 edges' rows. Head = 16 features = 4 lanes -> dot reduce is 2
// shfl_xor per 4 edges (0.5 DS/edge). v_dot2_f32_f16 for in-lane products.
// Softmax without max-subtraction (scores bounded, exp in fp32 range).
// Manual 2x unroll: 8 edges in flight.
__global__ __launch_bounds__(256) void gather_kernel(const __half* __restrict__ fth,
                                                     const int* __restrict__ row_ptr,
                                                     const int* __restrict__ csr,
                                                     float* __restrict__ out) {
    int node = __builtin_amdgcn_readfirstlane(blockIdx.x * 4 + (threadIdx.x >> 6));
    int lane = threadIdx.x & 63;
    int g = lane >> 4;     // edge slot within iteration
    int hl = lane & 15;    // feature-quad index; head = hl>>2

    int beg = row_ptr[node];
    int end = row_ptr[node + 1];

    H4 a = *(const H4*)&fth[(size_t)node * HF + 4 * hl];

    float acc0 = 0.f, acc1 = 0.f, acc2 = 0.f, acc3 = 0.f, lsum = 0.f;

    for (int i = beg; i < end; i += 8) {
        int idx0 = i + g;
        int idx1 = i + 4 + g;
        bool act0 = idx0 < end;
        bool act1 = idx1 < end;
        int s0 = csr[act0 ? idx0 : beg];
        int s1 = csr[act1 ? idx1 : beg];
        H4 v0 = *(const H4*)&fth[(size_t)s0 * HF + 4 * hl];
        H4 v1 = *(const H4*)&fth[(size_t)s1 * HF + 4 * hl];

        float p0 = dot4h(a, v0);
        float p1 = dot4h(a, v1);
        p0 += __shfl_xor(p0, 1, 64);  p1 += __shfl_xor(p1, 1, 64);
        p0 += __shfl_xor(p0, 2, 64);  p1 += __shfl_xor(p1, 2, 64);

        float w0 = act0 ? __expf(p0 * 0.25f) : 0.0f;
        float w1 = act1 ? __expf(p1 * 0.25f) : 0.0f;

        acc0 = fmaf(w0, (float)v0.a[0], acc0);
        acc1 = fmaf(w0, (float)v0.a[1], acc1);
        acc2 = fmaf(w0, (float)v0.b[0], acc2);
        acc3 = fmaf(w0, (float)v0.b[1], acc3);
        acc0 = fmaf(w1, (float)v1.a[0], acc0);
        acc1 = fmaf(w1, (float)v1.a[1], acc1);
        acc2 = fmaf(w1, (float)v1.b[0], acc2);
        acc3 = fmaf(w1, (float)v1.b[1], acc3);
        lsum += w0 + w1;
    }

    // reduce across the 4 edge-slots (lanes ^16, ^32 hold same features)
    acc0 += __shfl_xor(acc0, 16, 64);  acc0 += __shfl_xor(acc0, 32, 64);
    acc1 += __shfl_xor(acc1, 16, 64);  acc1 += __shfl_xor(acc1, 32, 64);
    acc2 += __shfl_xor(acc2, 16, 64);  acc2 += __shfl_xor(acc2, 32, 64);
    acc3 += __shfl_xor(acc3, 16, 64);  acc3 += __shfl_xor(acc3, 32, 64);
    lsum += __shfl_xor(lsum, 16, 64);  lsum += __shfl_xor(lsum, 32, 64);

    if (lane < 16) {
        float inv = (lsum > 0.0f) ? 1.0f / lsum : 0.0f;
        *(float4*)&out[(size_t)node * HF + 4 * hl] =
            make_float4(acc0 * inv, acc1 * inv, acc2 * inv, acc3 * inv);
    }
}

extern "C" void kernel_launch(void* const* d_in, const int* in_sizes, int n_in,
                              void* d_out, int out_size, void* d_ws, size_t ws_size,
                              hipStream_t stream) {
    const float* feat = (const float*)d_in[0];
    const float* W = (const float*)d_in[1];
    const int* src = (const int*)d_in[2];
    const int* dst = (const int*)d_in[3];
    float* out = (float*)d_out;

    // workspace layout
    __half* fth = (__half*)d_ws;                            // N*64 halves (6.4 MB)
    int* recs = (int*)(fth + (size_t)N_NODES * HF);         // NBUCKETS*BCAP ints (3.6 MB)
    int* csr = recs + (size_t)NBUCKETS * BCAP;              // E ints (3.2 MB)
    int* deg = csr + N_EDGES;                               // N ints   } one memset
    int* gcur = deg + N_NODES;                              // NBUCKETS } (contiguous)
    int* row_ptr = gcur + NBUCKETS;                         // N+1 ints
    int* cursor = row_ptr + N_NODES + 1;                    // N ints
    int* block_sums = cursor + N_NODES;                     // NBLK_SCAN ints

    hipMemsetAsync(deg, 0, (N_NODES + NBUCKETS) * sizeof(int), stream);
    gemm_kernel<<<GEMM_BLOCKS, 256, 0, stream>>>(feat, W, fth);
    bin_kernel<<<NBIN_BLOCKS, 256, 0, stream>>>(src, dst, gcur, recs, deg);
    scan1_kernel<<<NBLK_SCAN, 256, 0, stream>>>(deg, row_ptr, block_sums);
    scan2_kernel<<<1, 256, 0, stream>>>(block_sums);
    scan3_kernel<<<NBLK_SCAN, 256, 0, stream>>>(row_ptr, block_sums, cursor);
    scatter_kernel<<<NBUCKETS * 4, 256, 0, stream>>>(gcur, recs, cursor, csr);
    gather_kernel<<<N_NODES * 64 / 256, 256, 0, stream>>>(fth, row_ptr, csr, out);
}

// Round 11
// 142.856 us; speedup vs baseline: 1.3807x; 1.3807x over previous
//
#include <hip/hip_runtime.h>
#include <hip/hip_fp16.h>

#define N_NODES 50000
#define N_EDGES 800000
#define D_IN 128
#define HH 4
#define FF 16
#define HF 64  // HH*FF
#define NBUCKETS 196                 // ceil(N_NODES/256); bucket b covers dst in [b*256, b*256+256)
#define BCAP 4608                    // bucket capacity; Poisson(4096) + 8 sigma
#define CHUNK 2048                   // edges per bin_kernel block
#define NBIN_BLOCKS ((N_EDGES + CHUNK - 1) / CHUNK)  // 391
#define GEMM_BLOCKS ((N_NODES + 63) / 64)            // 782
#define SORT_K ((BCAP + 255) / 256)                  // 18 recs per thread in sort

struct __align__(8) Half4 { __half2 a, b; };

typedef _Float16 half2_v __attribute__((ext_vector_type(2)));
struct __align__(8) H4 { half2_v a, b; };

__device__ __forceinline__ float dot4h(H4 a, H4 v) {
#if __has_builtin(__builtin_amdgcn_fdot2)
    return __builtin_amdgcn_fdot2(a.a, v.a,
           __builtin_amdgcn_fdot2(a.b, v.b, 0.0f, false), false);
#else
    return (float)a.a[0] * (float)v.a[0] + (float)a.a[1] * (float)v.a[1]
         + (float)a.b[0] * (float)v.b[0] + (float)a.b[1] * (float)v.b[1];
#endif
}

// 256-entry exclusive scan with 2 barriers: wave shfl_up scan + 4-wave combine.
// Returns exclusive prefix of val; wsum must be __shared__ int[4].
__device__ __forceinline__ int block_excl_scan(int val, int* wsum) {
    int lane = threadIdx.x & 63;
    int wave = threadIdx.x >> 6;
    int incl = val;
#pragma unroll
    for (int off = 1; off < 64; off <<= 1) {
        int t = __shfl_up(incl, off, 64);
        if (lane >= off) incl += t;
    }
    if (lane == 63) wsum[wave] = incl;
    __syncthreads();
    if (threadIdx.x == 0) {
        int a = 0;
#pragma unroll
        for (int w = 0; w < 4; ++w) { int t = wsum[w]; wsum[w] = a; a += t; }
    }
    __syncthreads();
    return incl + wsum[wave] - val;
}

// ---------------- GEMM: ft[N,64] = feat[N,128] @ W[128,64], fp16 output ----------------
__global__ __launch_bounds__(256, 2) void gemm_kernel(const float* __restrict__ feat,
                                                      const float* __restrict__ W,
                                                      __half* __restrict__ fth) {
    __shared__ float As[64][132];   // padded: row stride 132 breaks 4-way bank conflict
    __shared__ float Bs[D_IN][HF];

    {
        const float4* W4 = (const float4*)W;
        float4* B4 = (float4*)Bs;
#pragma unroll
        for (int i = 0; i < 8; ++i) {
            int idx = threadIdx.x + 256 * i;
            B4[idx] = W4[idx];
        }
    }
    {
        int row0 = blockIdx.x * 64;
        const float4* F4 = (const float4*)feat;
#pragma unroll
        for (int i = 0; i < 8; ++i) {
            int idx = threadIdx.x + 256 * i;
            int r = idx >> 5;
            int c4 = idx & 31;
            float4 v = make_float4(0.f, 0.f, 0.f, 0.f);
            int row = row0 + r;
            if (row < N_NODES) v = F4[(size_t)row * 32 + c4];
            *(float4*)&As[r][c4 * 4] = v;
        }
    }
    __syncthreads();

    const int tr = threadIdx.x >> 4;
    const int tc = threadIdx.x & 15;

    float acc[4][4] = {};
#pragma unroll 8
    for (int k = 0; k < D_IN; k += 4) {
        float av[4][4], bv[4][4];
#pragma unroll
        for (int i = 0; i < 4; ++i) {
            float4 a = *(const float4*)&As[tr * 4 + i][k];
            av[i][0] = a.x; av[i][1] = a.y; av[i][2] = a.z; av[i][3] = a.w;
        }
#pragma unroll
        for (int j = 0; j < 4; ++j) {
            float4 b = *(const float4*)&Bs[k + j][tc * 4];
            bv[j][0] = b.x; bv[j][1] = b.y; bv[j][2] = b.z; bv[j][3] = b.w;
        }
#pragma unroll
        for (int i = 0; i < 4; ++i)
#pragma unroll
            for (int j = 0; j < 4; ++j)
#pragma unroll
                for (int c = 0; c < 4; ++c)
                    acc[i][c] = fmaf(av[i][j], bv[j][c], acc[i][c]);
    }

    int row0 = blockIdx.x * 64;
#pragma unroll
    for (int i = 0; i < 4; ++i) {
        int row = row0 + tr * 4 + i;
        if (row < N_NODES) {
            Half4 h;
            h.a = __floats2half2_rn(acc[i][0], acc[i][1]);
            h.b = __floats2half2_rn(acc[i][2], acc[i][3]);
            *(Half4*)&fth[(size_t)row * HF + tc * 4] = h;
        }
    }
}

// ---------------- pass 1: bin edges into 196 dst-buckets ----------------
// rec = src(16b) | (dst&255)<<16 | bucket<<24. NOTE: bucket>=128 makes rec
// NEGATIVE -- never use sign tests on recs (R10's bug). LDS counting sort per
// block, block-parallel flush in ~10-int runs per bucket. ~6 barriers total.
__global__ __launch_bounds__(256) void bin_kernel(const int* __restrict__ src,
                                                  const int* __restrict__ dst,
                                                  int* __restrict__ gcur,
                                                  int* __restrict__ recs) {
    __shared__ int hist[256];
    __shared__ int offs[256];
    __shared__ int cur[256];
    __shared__ int gbase[256];
    __shared__ int wsum[4];
    __shared__ int lrec[CHUNK];

    int tid = threadIdx.x;
    int e0 = blockIdx.x * CHUNK;
    int n = N_EDGES - e0; if (n > CHUNK) n = CHUNK;

    hist[tid] = 0;
    __syncthreads();

    int myrec[CHUNK / 256];
    int myb[CHUNK / 256];
#pragma unroll
    for (int k = 0; k < CHUNK / 256; ++k) {
        int idx = tid + k * 256;
        myb[k] = -1;
        if (idx < n) {
            int s = src[e0 + idx];
            int d = dst[e0 + idx];
            int b = d >> 8;
            myrec[k] = s | ((d & 255) << 16) | (b << 24);
            myb[k] = b;
            atomicAdd(&hist[b], 1);
        }
    }
    __syncthreads();

    int val = hist[tid];
    int excl = block_excl_scan(val, wsum);
    offs[tid] = excl;
    cur[tid] = excl;
    if (val > 0) gbase[tid] = atomicAdd(&gcur[tid], val);  // val>0 only for tid<NBUCKETS
    __syncthreads();

#pragma unroll
    for (int k = 0; k < CHUNK / 256; ++k) {
        if (myb[k] >= 0) {
            int p = atomicAdd(&cur[myb[k]], 1);
            lrec[p] = myrec[k];
        }
    }
    __syncthreads();

    // parallel flush: bucket id is in the record ((r>>24)&255 is sign-safe)
    for (int i = tid; i < n; i += 256) {
        int r = lrec[i];
        int b = (r >> 24) & 255;
        int pos = gbase[b] + (i - offs[b]);
        if (pos < BCAP) recs[(size_t)b * BCAP + pos] = r;
    }
}

// ---------------- pass 2: per-bucket counting sort -> CSR ----------------
// Single global read pass (recs -> registers, fully unrolled), INDEX-based
// validity (recs with bucket>=128 are negative, so no sign sentinels!),
// wave-scan hist, scatter from registers into the bucket's L2-hot window.
__global__ __launch_bounds__(256) void sort_kernel(const int* __restrict__ gcur,
                                                   const int* __restrict__ recs,
                                                   int* __restrict__ csr,
                                                   int* __restrict__ row_beg,
                                                   int* __restrict__ row_end) {
    __shared__ int lhist[256];
    __shared__ int lcur[256];
    __shared__ int wsum[4];

    int tid = threadIdx.x;
    int b = blockIdx.x;
    int cnt = gcur[b]; if (cnt > BCAP) cnt = BCAP;
    const int* rp = recs + (size_t)b * BCAP;

    lhist[tid] = 0;
    __syncthreads();

    int rk[SORT_K];
#pragma unroll
    for (int k = 0; k < SORT_K; ++k) {
        int i = tid + k * 256;
        bool valid = i < cnt;
        rk[k] = valid ? rp[i] : 0;
        if (valid) atomicAdd(&lhist[(rk[k] >> 16) & 255], 1);
    }
    __syncthreads();

    int val = lhist[tid];
    int excl = block_excl_scan(val, wsum);
    lcur[tid] = excl;
    __syncthreads();

    int base = b * BCAP;
#pragma unroll
    for (int k = 0; k < SORT_K; ++k) {
        int i = tid + k * 256;
        if (i < cnt) {
            int p = atomicAdd(&lcur[(rk[k] >> 16) & 255], 1);
            csr[base + p] = rk[k] & 0xFFFF;  // src id
        }
    }

    int node = (b << 8) + tid;
    if (node < N_NODES) {
        row_beg[node] = base + excl;
        row_end[node] = base + excl + val;
    }
}

// ---------------- fused gather: one wave per node, FOUR edges per load ----------------
// lane = g*16 + hl: g = edge slot (0..3), hl = feature-quad (features 4hl..4hl+3
// as half4). 16 lanes cover a 64-feature row -> one dwordx2 per lane fetches 4
// edges' rows per wave-load. Head = 4 lanes -> 2 shfl_xor per 4 edges. 2x unroll.
// Softmax without max-subtraction (scores bounded, exp in fp32 range).
__global__ __launch_bounds__(256) void gather_kernel(const __half* __restrict__ fth,
                                                     const int* __restrict__ row_beg,
                                                     const int* __restrict__ row_end,
                                                     const int* __restrict__ csr,
                                                     float* __restrict__ out) {
    int node = __builtin_amdgcn_readfirstlane(blockIdx.x * 4 + (threadIdx.x >> 6));
    int lane = threadIdx.x & 63;
    int g = lane >> 4;     // edge slot within iteration
    int hl = lane & 15;    // feature-quad index

    int beg = row_beg[node];
    int end = row_end[node];

    H4 a = *(const H4*)&fth[(size_t)node * HF + 4 * hl];

    float acc0 = 0.f, acc1 = 0.f, acc2 = 0.f, acc3 = 0.f, lsum = 0.f;

    for (int i = beg; i < end; i += 8) {
        int idx0 = i + g;
        int idx1 = i + 4 + g;
        bool act0 = idx0 < end;
        bool act1 = idx1 < end;
        int s0 = csr[act0 ? idx0 : beg];
        int s1 = csr[act1 ? idx1 : beg];
        H4 v0 = *(const H4*)&fth[(size_t)s0 * HF + 4 * hl];
        H4 v1 = *(const H4*)&fth[(size_t)s1 * HF + 4 * hl];

        float p0 = dot4h(a, v0);
        float p1 = dot4h(a, v1);
        p0 += __shfl_xor(p0, 1, 64);  p1 += __shfl_xor(p1, 1, 64);
        p0 += __shfl_xor(p0, 2, 64);  p1 += __shfl_xor(p1, 2, 64);

        float w0 = act0 ? __expf(p0 * 0.25f) : 0.0f;
        float w1 = act1 ? __expf(p1 * 0.25f) : 0.0f;

        acc0 = fmaf(w0, (float)v0.a[0], acc0);
        acc1 = fmaf(w0, (float)v0.a[1], acc1);
        acc2 = fmaf(w0, (float)v0.b[0], acc2);
        acc3 = fmaf(w0, (float)v0.b[1], acc3);
        acc0 = fmaf(w1, (float)v1.a[0], acc0);
        acc1 = fmaf(w1, (float)v1.a[1], acc1);
        acc2 = fmaf(w1, (float)v1.b[0], acc2);
        acc3 = fmaf(w1, (float)v1.b[1], acc3);
        lsum += w0 + w1;
    }

    // reduce across the 4 edge-slots (lanes ^16, ^32 hold same features)
    acc0 += __shfl_xor(acc0, 16, 64);  acc0 += __shfl_xor(acc0, 32, 64);
    acc1 += __shfl_xor(acc1, 16, 64);  acc1 += __shfl_xor(acc1, 32, 64);
    acc2 += __shfl_xor(acc2, 16, 64);  acc2 += __shfl_xor(acc2, 32, 64);
    acc3 += __shfl_xor(acc3, 16, 64);  acc3 += __shfl_xor(acc3, 32, 64);
    lsum += __shfl_xor(lsum, 16, 64);  lsum += __shfl_xor(lsum, 32, 64);

    if (lane < 16) {
        float inv = (lsum > 0.0f) ? 1.0f / lsum : 0.0f;
        *(float4*)&out[(size_t)node * HF + 4 * hl] =
            make_float4(acc0 * inv, acc1 * inv, acc2 * inv, acc3 * inv);
    }
}

extern "C" void kernel_launch(void* const* d_in, const int* in_sizes, int n_in,
                              void* d_out, int out_size, void* d_ws, size_t ws_size,
                              hipStream_t stream) {
    const float* feat = (const float*)d_in[0];
    const float* W = (const float*)d_in[1];
    const int* src = (const int*)d_in[2];
    const int* dst = (const int*)d_in[3];
    float* out = (float*)d_out;

    // workspace layout
    __half* fth = (__half*)d_ws;                            // N*64 halves (6.4 MB)
    int* recs = (int*)(fth + (size_t)N_NODES * HF);         // NBUCKETS*BCAP ints (3.6 MB)
    int* csr = recs + (size_t)NBUCKETS * BCAP;              // NBUCKETS*BCAP ints (3.6 MB)
    int* row_beg = csr + (size_t)NBUCKETS * BCAP;           // N ints
    int* row_end = row_beg + N_NODES;                       // N ints
    int* gcur = row_end + N_NODES;                          // NBUCKETS ints

    hipMemsetAsync(gcur, 0, NBUCKETS * sizeof(int), stream);
    gemm_kernel<<<GEMM_BLOCKS, 256, 0, stream>>>(feat, W, fth);
    bin_kernel<<<NBIN_BLOCKS, 256, 0, stream>>>(src, dst, gcur, recs);
    sort_kernel<<<NBUCKETS, 256, 0, stream>>>(gcur, recs, csr, row_beg, row_end);
    gather_kernel<<<N_NODES * 64 / 256, 256, 0, stream>>>(fth, row_beg, row_end, csr, out);
}

// Round 12
// 142.485 us; speedup vs baseline: 1.3843x; 1.0026x over previous
//
#include <hip/hip_runtime.h>
#include <hip/hip_fp16.h>

#define N_NODES 50000
#define N_EDGES 800000
#define D_IN 128
#define HH 4
#define FF 16
#define HF 64  // HH*FF
#define NBUCKETS 196                 // ceil(N_NODES/256); bucket b covers dst in [b*256, b*256+256)
#define BCAP 4608                    // bucket capacity; Poisson(4096) + 8 sigma
#define CHUNK 2048                   // edges per bin block
#define NBIN_BLOCKS ((N_EDGES + CHUNK - 1) / CHUNK)  // 391
#define GEMM_BLOCKS ((N_NODES + 63) / 64)            // 782
#define SORT_K ((BCAP + 255) / 256)                  // 18 recs per thread in sort

struct __align__(8) Half4 { __half2 a, b; };

typedef _Float16 half2_v __attribute__((ext_vector_type(2)));
struct __align__(8) H4 { half2_v a, b; };

__device__ __forceinline__ float dot4h(H4 a, H4 v) {
#if __has_builtin(__builtin_amdgcn_fdot2)
    return __builtin_amdgcn_fdot2(a.a, v.a,
           __builtin_amdgcn_fdot2(a.b, v.b, 0.0f, false), false);
#else
    return (float)a.a[0] * (float)v.a[0] + (float)a.a[1] * (float)v.a[1]
         + (float)a.b[0] * (float)v.b[0] + (float)a.b[1] * (float)v.b[1];
#endif
}

// 256-entry exclusive scan with 2 barriers: wave shfl_up scan + 4-wave combine.
__device__ __forceinline__ int block_excl_scan(int val, int* wsum) {
    int lane = threadIdx.x & 63;
    int wave = threadIdx.x >> 6;
    int incl = val;
#pragma unroll
    for (int off = 1; off < 64; off <<= 1) {
        int t = __shfl_up(incl, off, 64);
        if (lane >= off) incl += t;
    }
    if (lane == 63) wsum[wave] = incl;
    __syncthreads();
    if (threadIdx.x == 0) {
        int a = 0;
#pragma unroll
        for (int w = 0; w < 4; ++w) { int t = wsum[w]; wsum[w] = a; a += t; }
    }
    __syncthreads();
    return incl + wsum[wave] - val;
}

// LDS union: gemm path needs 65.8 KB, bin path 12.2 KB.
union SmemU {
    struct {
        float As[64][132];   // padded: stride 132 breaks 4-way bank conflict
        float Bs[D_IN][HF];
    } g;
    struct {
        int hist[256], offs[256], cur[256], gbase[256];
        int wsum[4];
        int lrec[CHUNK];
    } b;
};

// ---------------- fused: blocks [0,391) bin edges; blocks [391,1173) GEMM ----------------
// The two phases are data-independent; fusing overlaps bin's memory/LDS-atomic
// time with gemm's FMA time on co-resident blocks and saves a launch.
__global__ __launch_bounds__(256, 2) void gemm_bin_kernel(const float* __restrict__ feat,
                                                          const float* __restrict__ W,
                                                          const int* __restrict__ src,
                                                          const int* __restrict__ dst,
                                                          __half* __restrict__ fth,
                                                          int* __restrict__ gcur,
                                                          int* __restrict__ recs) {
    __shared__ SmemU smem;
    int tid = threadIdx.x;

    if (blockIdx.x < NBIN_BLOCKS) {
        // ---- bin: rec = src(16b) | (dst&255)<<16 | bucket<<24 (bucket>=128 -> rec
        // NEGATIVE: never sign-test recs). LDS counting sort, block-parallel flush.
        int e0 = blockIdx.x * CHUNK;
        int n = N_EDGES - e0; if (n > CHUNK) n = CHUNK;

        smem.b.hist[tid] = 0;
        __syncthreads();

        int myrec[CHUNK / 256];
        int myb[CHUNK / 256];
#pragma unroll
        for (int k = 0; k < CHUNK / 256; ++k) {
            int idx = tid + k * 256;
            myb[k] = -1;
            if (idx < n) {
                int s = src[e0 + idx];
                int d = dst[e0 + idx];
                int b = d >> 8;
                myrec[k] = s | ((d & 255) << 16) | (b << 24);
                myb[k] = b;
                atomicAdd(&smem.b.hist[b], 1);
            }
        }
        __syncthreads();

        int val = smem.b.hist[tid];
        int excl = block_excl_scan(val, smem.b.wsum);
        smem.b.offs[tid] = excl;
        smem.b.cur[tid] = excl;
        if (val > 0) smem.b.gbase[tid] = atomicAdd(&gcur[tid], val);  // val>0 only for tid<NBUCKETS
        __syncthreads();

#pragma unroll
        for (int k = 0; k < CHUNK / 256; ++k) {
            if (myb[k] >= 0) {
                int p = atomicAdd(&smem.b.cur[myb[k]], 1);
                smem.b.lrec[p] = myrec[k];
            }
        }
        __syncthreads();

        for (int i = tid; i < n; i += 256) {
            int r = smem.b.lrec[i];
            int b = (r >> 24) & 255;
            int pos = smem.b.gbase[b] + (i - smem.b.offs[b]);
            if (pos < BCAP) recs[(size_t)b * BCAP + pos] = r;
        }
    } else {
        // ---- GEMM: ft[N,64] = feat[N,128] @ W[128,64], fp16 out; 64x64 tile,
        // 4x4 register micro-tile (16 independent FMA chains).
        int gb = blockIdx.x - NBIN_BLOCKS;
        {
            const float4* W4 = (const float4*)W;
            float4* B4 = (float4*)smem.g.Bs;
#pragma unroll
            for (int i = 0; i < 8; ++i) {
                int idx = tid + 256 * i;
                B4[idx] = W4[idx];
            }
        }
        {
            int row0 = gb * 64;
            const float4* F4 = (const float4*)feat;
#pragma unroll
            for (int i = 0; i < 8; ++i) {
                int idx = tid + 256 * i;
                int r = idx >> 5;
                int c4 = idx & 31;
                float4 v = make_float4(0.f, 0.f, 0.f, 0.f);
                int row = row0 + r;
                if (row < N_NODES) v = F4[(size_t)row * 32 + c4];
                *(float4*)&smem.g.As[r][c4 * 4] = v;
            }
        }
        __syncthreads();

        const int tr = tid >> 4;
        const int tc = tid & 15;

        float acc[4][4] = {};
#pragma unroll 8
        for (int k = 0; k < D_IN; k += 4) {
            float av[4][4], bv[4][4];
#pragma unroll
            for (int i = 0; i < 4; ++i) {
                float4 a = *(const float4*)&smem.g.As[tr * 4 + i][k];
                av[i][0] = a.x; av[i][1] = a.y; av[i][2] = a.z; av[i][3] = a.w;
            }
#pragma unroll
            for (int j = 0; j < 4; ++j) {
                float4 b = *(const float4*)&smem.g.Bs[k + j][tc * 4];
                bv[j][0] = b.x; bv[j][1] = b.y; bv[j][2] = b.z; bv[j][3] = b.w;
            }
#pragma unroll
            for (int i = 0; i < 4; ++i)
#pragma unroll
                for (int j = 0; j < 4; ++j)
#pragma unroll
                    for (int c = 0; c < 4; ++c)
                        acc[i][c] = fmaf(av[i][j], bv[j][c], acc[i][c]);
        }

        int row0 = gb * 64;
#pragma unroll
        for (int i = 0; i < 4; ++i) {
            int row = row0 + tr * 4 + i;
            if (row < N_NODES) {
                Half4 h;
                h.a = __floats2half2_rn(acc[i][0], acc[i][1]);
                h.b = __floats2half2_rn(acc[i][2], acc[i][3]);
                *(Half4*)&fth[(size_t)row * HF + tc * 4] = h;
            }
        }
    }
}

// ---------------- pass 2: per-bucket counting sort -> ushort CSR ----------------
// Single global read pass (recs -> registers), INDEX-based validity (recs with
// bucket>=128 are negative -- no sign sentinels), wave-scan hist, scatter from
// registers into the bucket's L2-hot window. rows[node] = {beg, end} packed.
__global__ __launch_bounds__(256) void sort_kernel(const int* __restrict__ gcur,
                                                   const int* __restrict__ recs,
                                                   unsigned short* __restrict__ csr,
                                                   int2* __restrict__ rows) {
    __shared__ int lhist[256];
    __shared__ int lcur[256];
    __shared__ int wsum[4];

    int tid = threadIdx.x;
    int b = blockIdx.x;
    int cnt = gcur[b]; if (cnt > BCAP) cnt = BCAP;
    const int* rp = recs + (size_t)b * BCAP;

    lhist[tid] = 0;
    __syncthreads();

    int rk[SORT_K];
#pragma unroll
    for (int k = 0; k < SORT_K; ++k) {
        int i = tid + k * 256;
        bool valid = i < cnt;
        rk[k] = valid ? rp[i] : 0;
        if (valid) atomicAdd(&lhist[(rk[k] >> 16) & 255], 1);
    }
    __syncthreads();

    int val = lhist[tid];
    int excl = block_excl_scan(val, wsum);
    lcur[tid] = excl;
    __syncthreads();

    int base = b * BCAP;
#pragma unroll
    for (int k = 0; k < SORT_K; ++k) {
        int i = tid + k * 256;
        if (i < cnt) {
            int p = atomicAdd(&lcur[(rk[k] >> 16) & 255], 1);
            csr[base + p] = (unsigned short)(rk[k] & 0xFFFF);  // src id
        }
    }

    int node = (b << 8) + tid;
    if (node < N_NODES) rows[node] = make_int2(base + excl, base + excl + val);
}

// ---------------- fused gather: one wave per node, FOUR edges per load ----------------
// lane = g*16 + hl: g = edge slot (0..3), hl = feature-quad. 16 lanes cover a
// 64-feature row; head = 4 lanes -> 2 shfl_xor per 4 edges. 2x unroll (8 edges
// in flight). Softmax without max-subtraction (scores bounded, exp in fp32 range).
__global__ __launch_bounds__(256) void gather_kernel(const __half* __restrict__ fth,
                                                     const int2* __restrict__ rows,
                                                     const unsigned short* __restrict__ csr,
                                                     float* __restrict__ out) {
    int node = __builtin_amdgcn_readfirstlane(blockIdx.x * 4 + (threadIdx.x >> 6));
    int lane = threadIdx.x & 63;
    int g = lane >> 4;     // edge slot within iteration
    int hl = lane & 15;    // feature-quad index

    int2 be = rows[node];
    int beg = be.x;
    int end = be.y;

    H4 a = *(const H4*)&fth[(size_t)node * HF + 4 * hl];

    float acc0 = 0.f, acc1 = 0.f, acc2 = 0.f, acc3 = 0.f, lsum = 0.f;

    for (int i = beg; i < end; i += 8) {
        int idx0 = i + g;
        int idx1 = i + 4 + g;
        bool act0 = idx0 < end;
        bool act1 = idx1 < end;
        int s0 = csr[act0 ? idx0 : beg];
        int s1 = csr[act1 ? idx1 : beg];
        H4 v0 = *(const H4*)&fth[(size_t)s0 * HF + 4 * hl];
        H4 v1 = *(const H4*)&fth[(size_t)s1 * HF + 4 * hl];

        float p0 = dot4h(a, v0);
        float p1 = dot4h(a, v1);
        p0 += __shfl_xor(p0, 1, 64);  p1 += __shfl_xor(p1, 1, 64);
        p0 += __shfl_xor(p0, 2, 64);  p1 += __shfl_xor(p1, 2, 64);

        float w0 = act0 ? __expf(p0 * 0.25f) : 0.0f;
        float w1 = act1 ? __expf(p1 * 0.25f) : 0.0f;

        acc0 = fmaf(w0, (float)v0.a[0], acc0);
        acc1 = fmaf(w0, (float)v0.a[1], acc1);
        acc2 = fmaf(w0, (float)v0.b[0], acc2);
        acc3 = fmaf(w0, (float)v0.b[1], acc3);
        acc0 = fmaf(w1, (float)v1.a[0], acc0);
        acc1 = fmaf(w1, (float)v1.a[1], acc1);
        acc2 = fmaf(w1, (float)v1.b[0], acc2);
        acc3 = fmaf(w1, (float)v1.b[1], acc3);
        lsum += w0 + w1;
    }

    // reduce across the 4 edge-slots (lanes ^16, ^32 hold same features)
    acc0 += __shfl_xor(acc0, 16, 64);  acc0 += __shfl_xor(acc0, 32, 64);
    acc1 += __shfl_xor(acc1, 16, 64);  acc1 += __shfl_xor(acc1, 32, 64);
    acc2 += __shfl_xor(acc2, 16, 64);  acc2 += __shfl_xor(acc2, 32, 64);
    acc3 += __shfl_xor(acc3, 16, 64);  acc3 += __shfl_xor(acc3, 32, 64);
    lsum += __shfl_xor(lsum, 16, 64);  lsum += __shfl_xor(lsum, 32, 64);

    if (lane < 16) {
        float inv = (lsum > 0.0f) ? 1.0f / lsum : 0.0f;
        *(float4*)&out[(size_t)node * HF + 4 * hl] =
            make_float4(acc0 * inv, acc1 * inv, acc2 * inv, acc3 * inv);
    }
}

extern "C" void kernel_launch(void* const* d_in, const int* in_sizes, int n_in,
                              void* d_out, int out_size, void* d_ws, size_t ws_size,
                              hipStream_t stream) {
    const float* feat = (const float*)d_in[0];
    const float* W = (const float*)d_in[1];
    const int* src = (const int*)d_in[2];
    const int* dst = (const int*)d_in[3];
    float* out = (float*)d_out;

    // workspace layout (all 16B-aligned)
    __half* fth = (__half*)d_ws;                             // N*64 halves (6.4 MB)
    int* recs = (int*)(fth + (size_t)N_NODES * HF);          // NBUCKETS*BCAP ints (3.6 MB)
    unsigned short* csr = (unsigned short*)(recs + (size_t)NBUCKETS * BCAP);  // 1.8 MB
    int2* rows = (int2*)(csr + (size_t)NBUCKETS * BCAP);     // N int2 (0.4 MB)
    int* gcur = (int*)(rows + N_NODES);                      // NBUCKETS ints

    hipMemsetAsync(gcur, 0, NBUCKETS * sizeof(int), stream);
    gemm_bin_kernel<<<NBIN_BLOCKS + GEMM_BLOCKS, 256, 0, stream>>>(feat, W, src, dst,
                                                                   fth, gcur, recs);
    sort_kernel<<<NBUCKETS, 256, 0, stream>>>(gcur, recs, csr, rows);
    gather_kernel<<<N_NODES * 64 / 256, 256, 0, stream>>>(fth, rows, csr, out);
}

// Round 13
// 140.255 us; speedup vs baseline: 1.4063x; 1.0159x over previous
//
#include <hip/hip_runtime.h>
#include <hip/hip_fp16.h>

#define N_NODES 50000
#define N_EDGES 800000
#define D_IN 128
#define HH 4
#define FF 16
#define HF 64  // HH*FF
#define NBUCKETS 196                 // ceil(N_NODES/256); bucket b covers dst in [b*256, b*256+256)
#define BCAP 4608                    // bucket capacity; Poisson(4096) + 8 sigma
#define CHUNK 2048                   // edges per bin block
#define NBIN_BLOCKS ((N_EDGES + CHUNK - 1) / CHUNK)  // 391
#define GEMM_BLOCKS ((N_NODES + 63) / 64)            // 782
#define SORT_K ((BCAP + 255) / 256)                  // 18 recs per thread in sort

struct __align__(8) Half4 { __half2 a, b; };

typedef _Float16 half2_v __attribute__((ext_vector_type(2)));
struct __align__(8) H4 { half2_v a, b; };

__device__ __forceinline__ float dot4h(H4 a, H4 v) {
#if __has_builtin(__builtin_amdgcn_fdot2)
    return __builtin_amdgcn_fdot2(a.a, v.a,
           __builtin_amdgcn_fdot2(a.b, v.b, 0.0f, false), false);
#else
    return (float)a.a[0] * (float)v.a[0] + (float)a.a[1] * (float)v.a[1]
         + (float)a.b[0] * (float)v.b[0] + (float)a.b[1] * (float)v.b[1];
#endif
}

// 256-entry exclusive scan with 2 barriers: wave shfl_up scan + 4-wave combine.
__device__ __forceinline__ int block_excl_scan(int val, int* wsum) {
    int lane = threadIdx.x & 63;
    int wave = threadIdx.x >> 6;
    int incl = val;
#pragma unroll
    for (int off = 1; off < 64; off <<= 1) {
        int t = __shfl_up(incl, off, 64);
        if (lane >= off) incl += t;
    }
    if (lane == 63) wsum[wave] = incl;
    __syncthreads();
    if (threadIdx.x == 0) {
        int a = 0;
#pragma unroll
        for (int w = 0; w < 4; ++w) { int t = wsum[w]; wsum[w] = a; a += t; }
    }
    __syncthreads();
    return incl + wsum[wave] - val;
}

// LDS union: gemm path needs 65.8 KB, bin path 3 KB.
union SmemU {
    struct {
        float As[64][132];   // padded: stride 132 breaks 4-way bank conflict
        float Bs[D_IN][HF];
    } g;
    struct {
        int hist[256], cur[256], gbase[256];
    } b;
};

// ---------------- fused: blocks [0,391) bin edges; blocks [391,1173) GEMM ----------------
// bin: rec = src(16b) | (dst&255)<<16 | bucket<<24 (bucket>=128 -> rec NEGATIVE:
// never sign-test recs). No scan, no LDS staging: hist -> global window alloc ->
// DIRECT global scatter at gbase[b]+cur[b]++. Slots fill bucket windows in ~10-int
// runs per block, so write lines still fill densely. 3 barriers total.
__global__ __launch_bounds__(256, 2) void gemm_bin_kernel(const float* __restrict__ feat,
                                                          const float* __restrict__ W,
                                                          const int* __restrict__ src,
                                                          const int* __restrict__ dst,
                                                          __half* __restrict__ fth,
                                                          int* __restrict__ gcur,
                                                          int* __restrict__ recs) {
    __shared__ SmemU smem;
    int tid = threadIdx.x;

    if (blockIdx.x < NBIN_BLOCKS) {
        int e0 = blockIdx.x * CHUNK;
        int n = N_EDGES - e0; if (n > CHUNK) n = CHUNK;

        smem.b.hist[tid] = 0;
        __syncthreads();

        int myrec[CHUNK / 256];
        int myb[CHUNK / 256];
#pragma unroll
        for (int k = 0; k < CHUNK / 256; ++k) {
            int idx = tid + k * 256;
            myb[k] = -1;
            if (idx < n) {
                int s = src[e0 + idx];
                int d = dst[e0 + idx];
                int b = d >> 8;
                myrec[k] = s | ((d & 255) << 16) | (b << 24);
                myb[k] = b;
                atomicAdd(&smem.b.hist[b], 1);
            }
        }
        __syncthreads();

        int val = smem.b.hist[tid];
        smem.b.cur[tid] = 0;
        if (val > 0) smem.b.gbase[tid] = atomicAdd(&gcur[tid], val);  // val>0 only for tid<NBUCKETS
        __syncthreads();

#pragma unroll
        for (int k = 0; k < CHUNK / 256; ++k) {
            int b = myb[k];
            if (b >= 0) {
                int pos = smem.b.gbase[b] + atomicAdd(&smem.b.cur[b], 1);
                if (pos < BCAP) recs[(size_t)b * BCAP + pos] = myrec[k];
            }
        }
    } else {
        // ---- GEMM: ft[N,64] = feat[N,128] @ W[128,64], fp16 out; 64x64 tile,
        // 4x4 register micro-tile (16 independent FMA chains).
        int gb = blockIdx.x - NBIN_BLOCKS;
        {
            const float4* W4 = (const float4*)W;
            float4* B4 = (float4*)smem.g.Bs;
#pragma unroll
            for (int i = 0; i < 8; ++i) {
                int idx = tid + 256 * i;
                B4[idx] = W4[idx];
            }
        }
        {
            int row0 = gb * 64;
            const float4* F4 = (const float4*)feat;
#pragma unroll
            for (int i = 0; i < 8; ++i) {
                int idx = tid + 256 * i;
                int r = idx >> 5;
                int c4 = idx & 31;
                float4 v = make_float4(0.f, 0.f, 0.f, 0.f);
                int row = row0 + r;
                if (row < N_NODES) v = F4[(size_t)row * 32 + c4];
                *(float4*)&smem.g.As[r][c4 * 4] = v;
            }
        }
        __syncthreads();

        const int tr = tid >> 4;
        const int tc = tid & 15;

        float acc[4][4] = {};
#pragma unroll 8
        for (int k = 0; k < D_IN; k += 4) {
            float av[4][4], bv[4][4];
#pragma unroll
            for (int i = 0; i < 4; ++i) {
                float4 a = *(const float4*)&smem.g.As[tr * 4 + i][k];
                av[i][0] = a.x; av[i][1] = a.y; av[i][2] = a.z; av[i][3] = a.w;
            }
#pragma unroll
            for (int j = 0; j < 4; ++j) {
                float4 b = *(const float4*)&smem.g.Bs[k + j][tc * 4];
                bv[j][0] = b.x; bv[j][1] = b.y; bv[j][2] = b.z; bv[j][3] = b.w;
            }
#pragma unroll
            for (int i = 0; i < 4; ++i)
#pragma unroll
                for (int j = 0; j < 4; ++j)
#pragma unroll
                    for (int c = 0; c < 4; ++c)
                        acc[i][c] = fmaf(av[i][j], bv[j][c], acc[i][c]);
        }

        int row0 = gb * 64;
#pragma unroll
        for (int i = 0; i < 4; ++i) {
            int row = row0 + tr * 4 + i;
            if (row < N_NODES) {
                Half4 h;
                h.a = __floats2half2_rn(acc[i][0], acc[i][1]);
                h.b = __floats2half2_rn(acc[i][2], acc[i][3]);
                *(Half4*)&fth[(size_t)row * HF + tc * 4] = h;
            }
        }
    }
}

// ---------------- pass 2: per-bucket counting sort -> ushort CSR ----------------
// Single global read pass (recs -> registers), INDEX-based validity (recs with
// bucket>=128 are negative -- no sign sentinels), wave-scan hist, scatter from
// registers into the bucket's L2-hot window. rows[node] = {beg, end} packed.
__global__ __launch_bounds__(256) void sort_kernel(const int* __restrict__ gcur,
                                                   const int* __restrict__ recs,
                                                   unsigned short* __restrict__ csr,
                                                   int2* __restrict__ rows) {
    __shared__ int lhist[256];
    __shared__ int lcur[256];
    __shared__ int wsum[4];

    int tid = threadIdx.x;
    int b = blockIdx.x;
    int cnt = gcur[b]; if (cnt > BCAP) cnt = BCAP;
    const int* rp = recs + (size_t)b * BCAP;

    lhist[tid] = 0;
    __syncthreads();

    int rk[SORT_K];
#pragma unroll
    for (int k = 0; k < SORT_K; ++k) {
        int i = tid + k * 256;
        bool valid = i < cnt;
        rk[k] = valid ? rp[i] : 0;
        if (valid) atomicAdd(&lhist[(rk[k] >> 16) & 255], 1);
    }
    __syncthreads();

    int val = lhist[tid];
    int excl = block_excl_scan(val, wsum);
    lcur[tid] = excl;
    __syncthreads();

    int base = b * BCAP;
#pragma unroll
    for (int k = 0; k < SORT_K; ++k) {
        int i = tid + k * 256;
        if (i < cnt) {
            int p = atomicAdd(&lcur[(rk[k] >> 16) & 255], 1);
            csr[base + p] = (unsigned short)(rk[k] & 0xFFFF);  // src id
        }
    }

    int node = (b << 8) + tid;
    if (node < N_NODES) rows[node] = make_int2(base + excl, base + excl + val);
}

// ---------------- fused gather: one wave per node, SIXTEEN edges in flight ----------------
// lane = g*16 + hl: g = edge slot (0..3), hl = feature-quad. 16 lanes cover a
// 64-feature row; head = 4 lanes -> 2 shfl_xor per 4 edges. 4x unroll: deg<=16
// (54% of nodes, Poisson(16)) completes in ONE iteration. Softmax without
// max-subtraction (scores bounded, exp in fp32 range).
__global__ __launch_bounds__(256) void gather_kernel(const __half* __restrict__ fth,
                                                     const int2* __restrict__ rows,
                                                     const unsigned short* __restrict__ csr,
                                                     float* __restrict__ out) {
    int node = __builtin_amdgcn_readfirstlane(blockIdx.x * 4 + (threadIdx.x >> 6));
    int lane = threadIdx.x & 63;
    int g = lane >> 4;     // edge slot within group
    int hl = lane & 15;    // feature-quad index

    int2 be = rows[node];
    int beg = be.x;
    int end = be.y;

    H4 a = *(const H4*)&fth[(size_t)node * HF + 4 * hl];

    float acc0 = 0.f, acc1 = 0.f, acc2 = 0.f, acc3 = 0.f, lsum = 0.f;

    for (int i = beg; i < end; i += 16) {
        int s[4];
        bool act[4];
        H4 v[4];
        float p[4];
#pragma unroll
        for (int u = 0; u < 4; ++u) {
            int idx = i + 4 * u + g;
            act[u] = idx < end;
            s[u] = csr[act[u] ? idx : beg];
        }
#pragma unroll
        for (int u = 0; u < 4; ++u) v[u] = *(const H4*)&fth[(size_t)s[u] * HF + 4 * hl];
#pragma unroll
        for (int u = 0; u < 4; ++u) p[u] = dot4h(a, v[u]);
#pragma unroll
        for (int u = 0; u < 4; ++u) p[u] += __shfl_xor(p[u], 1, 64);
#pragma unroll
        for (int u = 0; u < 4; ++u) p[u] += __shfl_xor(p[u], 2, 64);
#pragma unroll
        for (int u = 0; u < 4; ++u) {
            float w = act[u] ? __expf(p[u] * 0.25f) : 0.0f;
            acc0 = fmaf(w, (float)v[u].a[0], acc0);
            acc1 = fmaf(w, (float)v[u].a[1], acc1);
            acc2 = fmaf(w, (float)v[u].b[0], acc2);
            acc3 = fmaf(w, (float)v[u].b[1], acc3);
            lsum += w;
        }
    }

    // reduce across the 4 edge-slots (lanes ^16, ^32 hold same features)
    acc0 += __shfl_xor(acc0, 16, 64);  acc0 += __shfl_xor(acc0, 32, 64);
    acc1 += __shfl_xor(acc1, 16, 64);  acc1 += __shfl_xor(acc1, 32, 64);
    acc2 += __shfl_xor(acc2, 16, 64);  acc2 += __shfl_xor(acc2, 32, 64);
    acc3 += __shfl_xor(acc3, 16, 64);  acc3 += __shfl_xor(acc3, 32, 64);
    lsum += __shfl_xor(lsum, 16, 64);  lsum += __shfl_xor(lsum, 32, 64);

    if (lane < 16) {
        float inv = (lsum > 0.0f) ? 1.0f / lsum : 0.0f;
        *(float4*)&out[(size_t)node * HF + 4 * hl] =
            make_float4(acc0 * inv, acc1 * inv, acc2 * inv, acc3 * inv);
    }
}

extern "C" void kernel_launch(void* const* d_in, const int* in_sizes, int n_in,
                              void* d_out, int out_size, void* d_ws, size_t ws_size,
                              hipStream_t stream) {
    const float* feat = (const float*)d_in[0];
    const float* W = (const float*)d_in[1];
    const int* src = (const int*)d_in[2];
    const int* dst = (const int*)d_in[3];
    float* out = (float*)d_out;

    // workspace layout (all 16B-aligned)
    __half* fth = (__half*)d_ws;                             // N*64 halves (6.4 MB)
    int* recs = (int*)(fth + (size_t)N_NODES * HF);          // NBUCKETS*BCAP ints (3.6 MB)
    unsigned short* csr = (unsigned short*)(recs + (size_t)NBUCKETS * BCAP);  // 1.8 MB
    int2* rows = (int2*)(csr + (size_t)NBUCKETS * BCAP);     // N int2 (0.4 MB)
    int* gcur = (int*)(rows + N_NODES);                      // NBUCKETS ints

    hipMemsetAsync(gcur, 0, NBUCKETS * sizeof(int), stream);
    gemm_bin_kernel<<<NBIN_BLOCKS + GEMM_BLOCKS, 256, 0, stream>>>(feat, W, src, dst,
                                                                   fth, gcur, recs);
    sort_kernel<<<NBUCKETS, 256, 0, stream>>>(gcur, recs, csr, rows);
    gather_kernel<<<N_NODES * 64 / 256, 256, 0, stream>>>(fth, rows, csr, out);
}

// Round 14
// 138.587 us; speedup vs baseline: 1.4233x; 1.0120x over previous
//
#include <hip/hip_runtime.h>
#include <hip/hip_fp16.h>

#define N_NODES 50000
#define N_EDGES 800000
#define D_IN 128
#define HH 4
#define FF 16
#define HF 64  // HH*FF
#define NBUCKETS 392                 // ceil(N_NODES/128); bucket b covers dst in [b*128, b*128+128)
#define BCAP 2560                    // bucket capacity; Poisson(2048) + 11 sigma
#define CHUNK 2048                   // edges per bin block
#define NBIN_BLOCKS ((N_EDGES + CHUNK - 1) / CHUNK)  // 391
#define GEMM_BLOCKS ((N_NODES + 63) / 64)            // 782
#define SORT_K (BCAP / 256)                          // 10 recs per thread in sort

struct __align__(8) Half4 { __half2 a, b; };

typedef _Float16 half2_v __attribute__((ext_vector_type(2)));
struct __align__(8) H4 { half2_v a, b; };

__device__ __forceinline__ float dot4h(H4 a, H4 v) {
#if __has_builtin(__builtin_amdgcn_fdot2)
    return __builtin_amdgcn_fdot2(a.a, v.a,
           __builtin_amdgcn_fdot2(a.b, v.b, 0.0f, false), false);
#else
    return (float)a.a[0] * (float)v.a[0] + (float)a.a[1] * (float)v.a[1]
         + (float)a.b[0] * (float)v.b[0] + (float)a.b[1] * (float)v.b[1];
#endif
}

// 256-entry exclusive scan with 2 barriers: wave shfl_up scan + 4-wave combine.
__device__ __forceinline__ int block_excl_scan(int val, int* wsum) {
    int lane = threadIdx.x & 63;
    int wave = threadIdx.x >> 6;
    int incl = val;
#pragma unroll
    for (int off = 1; off < 64; off <<= 1) {
        int t = __shfl_up(incl, off, 64);
        if (lane >= off) incl += t;
    }
    if (lane == 63) wsum[wave] = incl;
    __syncthreads();
    if (threadIdx.x == 0) {
        int a = 0;
#pragma unroll
        for (int w = 0; w < 4; ++w) { int t = wsum[w]; wsum[w] = a; a += t; }
    }
    __syncthreads();
    return incl + wsum[wave] - val;
}

// LDS union: gemm path needs 65.8 KB, bin path 6 KB.
union SmemU {
    struct {
        float As[64][132];   // padded: stride 132 breaks 4-way bank conflict
        float Bs[D_IN][HF];
    } g;
    struct {
        int hist[512], cur[512], gbase[512];  // 392 used
    } b;
};

// ---------------- fused: blocks [0,391) bin edges; blocks [391,1173) GEMM ----------------
// bin: rec = src(16b) | (dst&127)<<16 | bucket<<23 (bucket>=256 -> rec NEGATIVE:
// never sign-test recs; extract with unsigned >>23). No scan, no LDS staging:
// hist -> global window alloc -> direct global scatter at gbase[b]+cur[b]++.
// Slots fill bucket windows in ~5-int runs per block. 3 barriers total.
__global__ __launch_bounds__(256, 2) void gemm_bin_kernel(const float* __restrict__ feat,
                                                          const float* __restrict__ W,
                                                          const int* __restrict__ src,
                                                          const int* __restrict__ dst,
                                                          __half* __restrict__ fth,
                                                          int* __restrict__ gcur,
                                                          int* __restrict__ recs) {
    __shared__ SmemU smem;
    int tid = threadIdx.x;

    if (blockIdx.x < NBIN_BLOCKS) {
        int e0 = blockIdx.x * CHUNK;
        int n = N_EDGES - e0; if (n > CHUNK) n = CHUNK;

        smem.b.hist[tid] = 0;
        smem.b.hist[tid + 256] = 0;
        __syncthreads();

        int myrec[CHUNK / 256];
        int myb[CHUNK / 256];
#pragma unroll
        for (int k = 0; k < CHUNK / 256; ++k) {
            int idx = tid + k * 256;
            myb[k] = -1;
            if (idx < n) {
                int s = src[e0 + idx];
                int d = dst[e0 + idx];
                int b = d >> 7;
                myrec[k] = s | ((d & 127) << 16) | (b << 23);
                myb[k] = b;
                atomicAdd(&smem.b.hist[b], 1);
            }
        }
        __syncthreads();

#pragma unroll
        for (int j = 0; j < 2; ++j) {
            int idx = tid + j * 256;
            int val = smem.b.hist[idx];
            smem.b.cur[idx] = 0;
            if (val > 0) smem.b.gbase[idx] = atomicAdd(&gcur[idx], val);  // val>0 only for idx<NBUCKETS
        }
        __syncthreads();

#pragma unroll
        for (int k = 0; k < CHUNK / 256; ++k) {
            int b = myb[k];
            if (b >= 0) {
                int pos = smem.b.gbase[b] + atomicAdd(&smem.b.cur[b], 1);
                if (pos < BCAP) recs[(size_t)b * BCAP + pos] = myrec[k];
            }
        }
    } else {
        // ---- GEMM: ft[N,64] = feat[N,128] @ W[128,64], fp16 out; 64x64 tile,
        // 4x4 register micro-tile (16 independent FMA chains).
        int gb = blockIdx.x - NBIN_BLOCKS;
        {
            const float4* W4 = (const float4*)W;
            float4* B4 = (float4*)smem.g.Bs;
#pragma unroll
            for (int i = 0; i < 8; ++i) {
                int idx = tid + 256 * i;
                B4[idx] = W4[idx];
            }
        }
        {
            int row0 = gb * 64;
            const float4* F4 = (const float4*)feat;
#pragma unroll
            for (int i = 0; i < 8; ++i) {
                int idx = tid + 256 * i;
                int r = idx >> 5;
                int c4 = idx & 31;
                float4 v = make_float4(0.f, 0.f, 0.f, 0.f);
                int row = row0 + r;
                if (row < N_NODES) v = F4[(size_t)row * 32 + c4];
                *(float4*)&smem.g.As[r][c4 * 4] = v;
            }
        }
        __syncthreads();

        const int tr = tid >> 4;
        const int tc = tid & 15;

        float acc[4][4] = {};
#pragma unroll 8
        for (int k = 0; k < D_IN; k += 4) {
            float av[4][4], bv[4][4];
#pragma unroll
            for (int i = 0; i < 4; ++i) {
                float4 a = *(const float4*)&smem.g.As[tr * 4 + i][k];
                av[i][0] = a.x; av[i][1] = a.y; av[i][2] = a.z; av[i][3] = a.w;
            }
#pragma unroll
            for (int j = 0; j < 4; ++j) {
                float4 b = *(const float4*)&smem.g.Bs[k + j][tc * 4];
                bv[j][0] = b.x; bv[j][1] = b.y; bv[j][2] = b.z; bv[j][3] = b.w;
            }
#pragma unroll
            for (int i = 0; i < 4; ++i)
#pragma unroll
                for (int j = 0; j < 4; ++j)
#pragma unroll
                    for (int c = 0; c < 4; ++c)
                        acc[i][c] = fmaf(av[i][j], bv[j][c], acc[i][c]);
        }

        int row0 = gb * 64;
#pragma unroll
        for (int i = 0; i < 4; ++i) {
            int row = row0 + tr * 4 + i;
            if (row < N_NODES) {
                Half4 h;
                h.a = __floats2half2_rn(acc[i][0], acc[i][1]);
                h.b = __floats2half2_rn(acc[i][2], acc[i][3]);
                *(Half4*)&fth[(size_t)row * HF + tc * 4] = h;
            }
        }
    }
}

// ---------------- pass 2: per-bucket counting sort -> ushort CSR ----------------
// 392 blocks (1.5/CU). Single global read pass (recs -> registers), INDEX-based
// validity, wave-scan hist over 128 node slots, scatter from registers into the
// bucket's L2-hot window. rows[node] = {beg, end} packed.
__global__ __launch_bounds__(256) void sort_kernel(const int* __restrict__ gcur,
                                                   const int* __restrict__ recs,
                                                   unsigned short* __restrict__ csr,
                                                   int2* __restrict__ rows) {
    __shared__ int lhist[256];
    __shared__ int lcur[256];
    __shared__ int wsum[4];

    int tid = threadIdx.x;
    int b = blockIdx.x;
    int cnt = gcur[b]; if (cnt > BCAP) cnt = BCAP;
    const int* rp = recs + (size_t)b * BCAP;

    lhist[tid] = 0;
    __syncthreads();

    int rk[SORT_K];
#pragma unroll
    for (int k = 0; k < SORT_K; ++k) {
        int i = tid + k * 256;
        bool valid = i < cnt;
        rk[k] = valid ? rp[i] : 0;
        if (valid) atomicAdd(&lhist[(rk[k] >> 16) & 127], 1);
    }
    __syncthreads();

    int val = lhist[tid];                 // zero for tid >= 128
    int excl = block_excl_scan(val, wsum);
    lcur[tid] = excl;
    __syncthreads();

    int base = b * BCAP;
#pragma unroll
    for (int k = 0; k < SORT_K; ++k) {
        int i = tid + k * 256;
        if (i < cnt) {
            int p = atomicAdd(&lcur[(rk[k] >> 16) & 127], 1);
            csr[base + p] = (unsigned short)(rk[k] & 0xFFFF);  // src id
        }
    }

    if (tid < 128) {
        int node = (b << 7) + tid;
        if (node < N_NODES) rows[node] = make_int2(base + excl, base + excl + val);
    }
}

// ---------------- fused gather: one wave per node, SIXTEEN edges in flight ----------------
// lane = g*16 + hl: g = edge slot (0..3), hl = feature-quad. 16 lanes cover a
// 64-feature row; head = 4 lanes -> 2 shfl_xor per 4 edges. 4x unroll: deg<=16
// (54% of nodes, Poisson(16)) completes in ONE iteration. Softmax without
// max-subtraction (scores bounded, exp in fp32 range).
__global__ __launch_bounds__(256) void gather_kernel(const __half* __restrict__ fth,
                                                     const int2* __restrict__ rows,
                                                     const unsigned short* __restrict__ csr,
                                                     float* __restrict__ out) {
    int node = __builtin_amdgcn_readfirstlane(blockIdx.x * 4 + (threadIdx.x >> 6));
    int lane = threadIdx.x & 63;
    int g = lane >> 4;     // edge slot within group
    int hl = lane & 15;    // feature-quad index

    int2 be = rows[node];
    int beg = be.x;
    int end = be.y;

    H4 a = *(const H4*)&fth[(size_t)node * HF + 4 * hl];

    float acc0 = 0.f, acc1 = 0.f, acc2 = 0.f, acc3 = 0.f, lsum = 0.f;

    for (int i = beg; i < end; i += 16) {
        int s[4];
        bool act[4];
        H4 v[4];
        float p[4];
#pragma unroll
        for (int u = 0; u < 4; ++u) {
            int idx = i + 4 * u + g;
            act[u] = idx < end;
            s[u] = csr[act[u] ? idx : beg];
        }
#pragma unroll
        for (int u = 0; u < 4; ++u) v[u] = *(const H4*)&fth[(size_t)s[u] * HF + 4 * hl];
#pragma unroll
        for (int u = 0; u < 4; ++u) p[u] = dot4h(a, v[u]);
#pragma unroll
        for (int u = 0; u < 4; ++u) p[u] += __shfl_xor(p[u], 1, 64);
#pragma unroll
        for (int u = 0; u < 4; ++u) p[u] += __shfl_xor(p[u], 2, 64);
#pragma unroll
        for (int u = 0; u < 4; ++u) {
            float w = act[u] ? __expf(p[u] * 0.25f) : 0.0f;
            acc0 = fmaf(w, (float)v[u].a[0], acc0);
            acc1 = fmaf(w, (float)v[u].a[1], acc1);
            acc2 = fmaf(w, (float)v[u].b[0], acc2);
            acc3 = fmaf(w, (float)v[u].b[1], acc3);
            lsum += w;
        }
    }

    // reduce across the 4 edge-slots (lanes ^16, ^32 hold same features)
    acc0 += __shfl_xor(acc0, 16, 64);  acc0 += __shfl_xor(acc0, 32, 64);
    acc1 += __shfl_xor(acc1, 16, 64);  acc1 += __shfl_xor(acc1, 32, 64);
    acc2 += __shfl_xor(acc2, 16, 64);  acc2 += __shfl_xor(acc2, 32, 64);
    acc3 += __shfl_xor(acc3, 16, 64);  acc3 += __shfl_xor(acc3, 32, 64);
    lsum += __shfl_xor(lsum, 16, 64);  lsum += __shfl_xor(lsum, 32, 64);

    if (lane < 16) {
        float inv = (lsum > 0.0f) ? 1.0f / lsum : 0.0f;
        *(float4*)&out[(size_t)node * HF + 4 * hl] =
            make_float4(acc0 * inv, acc1 * inv, acc2 * inv, acc3 * inv);
    }
}

extern "C" void kernel_launch(void* const* d_in, const int* in_sizes, int n_in,
                              void* d_out, int out_size, void* d_ws, size_t ws_size,
                              hipStream_t stream) {
    const float* feat = (const float*)d_in[0];
    const float* W = (const float*)d_in[1];
    const int* src = (const int*)d_in[2];
    const int* dst = (const int*)d_in[3];
    float* out = (float*)d_out;

    // workspace layout (all 16B-aligned)
    __half* fth = (__half*)d_ws;                             // N*64 halves (6.4 MB)
    int* recs = (int*)(fth + (size_t)N_NODES * HF);          // NBUCKETS*BCAP ints (4.0 MB)
    unsigned short* csr = (unsigned short*)(recs + (size_t)NBUCKETS * BCAP);  // 2.0 MB
    int2* rows = (int2*)(csr + (size_t)NBUCKETS * BCAP);     // N int2 (0.4 MB)
    int* gcur = (int*)(rows + N_NODES);                      // NBUCKETS ints

    hipMemsetAsync(gcur, 0, NBUCKETS * sizeof(int), stream);
    gemm_bin_kernel<<<NBIN_BLOCKS + GEMM_BLOCKS, 256, 0, stream>>>(feat, W, src, dst,
                                                                   fth, gcur, recs);
    sort_kernel<<<NBUCKETS, 256, 0, stream>>>(gcur, recs, csr, rows);
    gather_kernel<<<N_NODES * 64 / 256, 256, 0, stream>>>(fth, rows, csr, out);
}

// Round 15
// 138.011 us; speedup vs baseline: 1.4292x; 1.0042x over previous
//
#include <hip/hip_runtime.h>
#include <hip/hip_fp16.h>

#define N_NODES 50000
#define N_EDGES 800000
#define D_IN 128
#define HH 4
#define FF 16
#define HF 64  // HH*FF
#define NBUCKETS 392                 // ceil(N_NODES/128); bucket b covers dst in [b*128, b*128+128)
#define BCAP 2560                    // bucket capacity; Poisson(2048) + 11 sigma
#define CHUNK 2048                   // edges per bin block
#define NBIN_BLOCKS ((N_EDGES + CHUNK - 1) / CHUNK)  // 391
#define GEMM_BLOCKS ((N_NODES + 63) / 64)            // 782
#define SORT_K (BCAP / 256)                          // 10 recs per thread in sort

struct __align__(8) Half4 { __half2 a, b; };

typedef _Float16 half2_v __attribute__((ext_vector_type(2)));
struct __align__(8) H4 { half2_v a, b; };

__device__ __forceinline__ float dot2acc(half2_v a, half2_v b, float acc) {
#if __has_builtin(__builtin_amdgcn_fdot2)
    return __builtin_amdgcn_fdot2(a, b, acc, false);
#else
    return acc + (float)a[0] * (float)b[0] + (float)a[1] * (float)b[1];
#endif
}

__device__ __forceinline__ float dot4h(H4 a, H4 v) {
    return dot2acc(a.a, v.a, dot2acc(a.b, v.b, 0.0f));
}

// 256-entry exclusive scan with 2 barriers: wave shfl_up scan + 4-wave combine.
__device__ __forceinline__ int block_excl_scan(int val, int* wsum) {
    int lane = threadIdx.x & 63;
    int wave = threadIdx.x >> 6;
    int incl = val;
#pragma unroll
    for (int off = 1; off < 64; off <<= 1) {
        int t = __shfl_up(incl, off, 64);
        if (lane >= off) incl += t;
    }
    if (lane == 63) wsum[wave] = incl;
    __syncthreads();
    if (threadIdx.x == 0) {
        int a = 0;
#pragma unroll
        for (int w = 0; w < 4; ++w) { int t = wsum[w]; wsum[w] = a; a += t; }
    }
    __syncthreads();
    return incl + wsum[wave] - val;
}

// ---------------- GEMM: ft[N,64] = feat[N,128] @ W[128,64], all-fp16 LDS ----------------
// As[64][132] halves (stride 264 B: 8B-aligned; 4-row delta = 264 words ≡ 8 mod 32
// -> the 4 broadcast addresses hit distinct banks). Bst = W TRANSPOSED [col][k],
// [64][136] halves (stride 272 B: 8B-aligned; 4-row delta ≡ 16 words -> 2-way
// conflict, which is free). Inner step: 8 ds_read_b64 + 32 v_dot2_f32_f16 per k4
// (vs 8 b128 + 64 fma in fp32). 34 KB LDS -> 4 blocks/CU.
__global__ __launch_bounds__(256, 4) void gemm_kernel(const float* __restrict__ feat,
                                                      const float* __restrict__ W,
                                                      __half* __restrict__ fth) {
    __shared__ __half As[64][132];
    __shared__ __half Bst[64][136];

    int tid = threadIdx.x;

    // stage W -> Bst (fp16, transposed): idx = k*16 + c4
    {
        const float4* W4 = (const float4*)W;
#pragma unroll
        for (int i = 0; i < 8; ++i) {
            int idx = tid + 256 * i;
            int k = idx >> 4;
            int c4 = idx & 15;
            float4 v = W4[idx];
            Bst[c4 * 4 + 0][k] = __float2half(v.x);
            Bst[c4 * 4 + 1][k] = __float2half(v.y);
            Bst[c4 * 4 + 2][k] = __float2half(v.z);
            Bst[c4 * 4 + 3][k] = __float2half(v.w);
        }
    }
    // stage feat tile -> As (fp16)
    {
        int row0 = blockIdx.x * 64;
        const float4* F4 = (const float4*)feat;
#pragma unroll
        for (int i = 0; i < 8; ++i) {
            int idx = tid + 256 * i;
            int r = idx >> 5;
            int c4 = idx & 31;
            float4 v = make_float4(0.f, 0.f, 0.f, 0.f);
            int row = row0 + r;
            if (row < N_NODES) v = F4[(size_t)row * 32 + c4];
            Half4 h;
            h.a = __floats2half2_rn(v.x, v.y);
            h.b = __floats2half2_rn(v.z, v.w);
            *(Half4*)&As[r][c4 * 4] = h;  // byte off = r*264 + c4*8, 8B-aligned
        }
    }
    __syncthreads();

    const int tr = tid >> 4;
    const int tc = tid & 15;

    float acc[4][4] = {};
#pragma unroll 4
    for (int k4 = 0; k4 < D_IN / 4; ++k4) {
        H4 a[4], b[4];
#pragma unroll
        for (int i = 0; i < 4; ++i) a[i] = *(const H4*)&As[tr * 4 + i][k4 * 4];
#pragma unroll
        for (int c = 0; c < 4; ++c) b[c] = *(const H4*)&Bst[tc * 4 + c][k4 * 4];
#pragma unroll
        for (int i = 0; i < 4; ++i)
#pragma unroll
            for (int c = 0; c < 4; ++c)
                acc[i][c] = dot2acc(a[i].b, b[c].b, dot2acc(a[i].a, b[c].a, acc[i][c]));
    }

    int row0 = blockIdx.x * 64;
#pragma unroll
    for (int i = 0; i < 4; ++i) {
        int row = row0 + tr * 4 + i;
        if (row < N_NODES) {
            Half4 h;
            h.a = __floats2half2_rn(acc[i][0], acc[i][1]);
            h.b = __floats2half2_rn(acc[i][2], acc[i][3]);
            *(Half4*)&fth[(size_t)row * HF + tc * 4] = h;
        }
    }
}

// ---------------- bin: edges -> 392 dst-buckets (standalone, 6 KB LDS) ----------------
// rec = src(16b) | (dst&127)<<16 | bucket<<23 (bucket>=256 -> rec NEGATIVE: never
// sign-test recs). hist -> global window alloc -> direct global scatter at
// gbase[b]+cur[b]++. 3 barriers; high occupancy now that it owns its LDS budget.
__global__ __launch_bounds__(256) void bin_kernel(const int* __restrict__ src,
                                                  const int* __restrict__ dst,
                                                  int* __restrict__ gcur,
                                                  int* __restrict__ recs) {
    __shared__ int hist[512], cur[512], gbase[512];  // 392 used

    int tid = threadIdx.x;
    int e0 = blockIdx.x * CHUNK;
    int n = N_EDGES - e0; if (n > CHUNK) n = CHUNK;

    hist[tid] = 0;
    hist[tid + 256] = 0;
    __syncthreads();

    int myrec[CHUNK / 256];
    int myb[CHUNK / 256];
#pragma unroll
    for (int k = 0; k < CHUNK / 256; ++k) {
        int idx = tid + k * 256;
        myb[k] = -1;
        if (idx < n) {
            int s = src[e0 + idx];
            int d = dst[e0 + idx];
            int b = d >> 7;
            myrec[k] = s | ((d & 127) << 16) | (b << 23);
            myb[k] = b;
            atomicAdd(&hist[b], 1);
        }
    }
    __syncthreads();

#pragma unroll
    for (int j = 0; j < 2; ++j) {
        int idx = tid + j * 256;
        int val = hist[idx];
        cur[idx] = 0;
        if (val > 0) gbase[idx] = atomicAdd(&gcur[idx], val);  // val>0 only for idx<NBUCKETS
    }
    __syncthreads();

#pragma unroll
    for (int k = 0; k < CHUNK / 256; ++k) {
        int b = myb[k];
        if (b >= 0) {
            int pos = gbase[b] + atomicAdd(&cur[b], 1);
            if (pos < BCAP) recs[(size_t)b * BCAP + pos] = myrec[k];
        }
    }
}

// ---------------- sort: per-bucket counting sort -> ushort CSR ----------------
// 392 blocks. Single global read pass (recs -> registers), INDEX-based validity,
// wave-scan hist over 128 node slots, scatter into the bucket's L2-hot window.
__global__ __launch_bounds__(256) void sort_kernel(const int* __restrict__ gcur,
                                                   const int* __restrict__ recs,
                                                   unsigned short* __restrict__ csr,
                                                   int2* __restrict__ rows) {
    __shared__ int lhist[256];
    __shared__ int lcur[256];
    __shared__ int wsum[4];

    int tid = threadIdx.x;
    int b = blockIdx.x;
    int cnt = gcur[b]; if (cnt > BCAP) cnt = BCAP;
    const int* rp = recs + (size_t)b * BCAP;

    lhist[tid] = 0;
    __syncthreads();

    int rk[SORT_K];
#pragma unroll
    for (int k = 0; k < SORT_K; ++k) {
        int i = tid + k * 256;
        bool valid = i < cnt;
        rk[k] = valid ? rp[i] : 0;
        if (valid) atomicAdd(&lhist[(rk[k] >> 16) & 127], 1);
    }
    __syncthreads();

    int val = lhist[tid];                 // zero for tid >= 128
    int excl = block_excl_scan(val, wsum);
    lcur[tid] = excl;
    __syncthreads();

    int base = b * BCAP;
#pragma unroll
    for (int k = 0; k < SORT_K; ++k) {
        int i = tid + k * 256;
        if (i < cnt) {
            int p = atomicAdd(&lcur[(rk[k] >> 16) & 127], 1);
            csr[base + p] = (unsigned short)(rk[k] & 0xFFFF);  // src id
        }
    }

    if (tid < 128) {
        int node = (b << 7) + tid;
        if (node < N_NODES) rows[node] = make_int2(base + excl, base + excl + val);
    }
}

// ---------------- fused gather: one wave per node, SIXTEEN edges in flight ----------------
// lane = g*16 + hl: g = edge slot (0..3), hl = feature-quad. 16 lanes cover a
// 64-feature row; head = 4 lanes -> 2 shfl_xor per 4 edges. Softmax without
// max-subtraction (scores bounded, exp in fp32 range).
__global__ __launch_bounds__(256) void gather_kernel(const __half* __restrict__ fth,
                                                     const int2* __restrict__ rows,
                                                     const unsigned short* __restrict__ csr,
                                                     float* __restrict__ out) {
    int node = __builtin_amdgcn_readfirstlane(blockIdx.x * 4 + (threadIdx.x >> 6));
    int lane = threadIdx.x & 63;
    int g = lane >> 4;     // edge slot within group
    int hl = lane & 15;    // feature-quad index

    int2 be = rows[node];
    int beg = be.x;
    int end = be.y;

    H4 a = *(const H4*)&fth[(size_t)node * HF + 4 * hl];

    float acc0 = 0.f, acc1 = 0.f, acc2 = 0.f, acc3 = 0.f, lsum = 0.f;

    for (int i = beg; i < end; i += 16) {
        int s[4];
        bool act[4];
        H4 v[4];
        float p[4];
#pragma unroll
        for (int u = 0; u < 4; ++u) {
            int idx = i + 4 * u + g;
            act[u] = idx < end;
            s[u] = csr[act[u] ? idx : beg];
        }
#pragma unroll
        for (int u = 0; u < 4; ++u) v[u] = *(const H4*)&fth[(size_t)s[u] * HF + 4 * hl];
#pragma unroll
        for (int u = 0; u < 4; ++u) p[u] = dot4h(a, v[u]);
#pragma unroll
        for (int u = 0; u < 4; ++u) p[u] += __shfl_xor(p[u], 1, 64);
#pragma unroll
        for (int u = 0; u < 4; ++u) p[u] += __shfl_xor(p[u], 2, 64);
#pragma unroll
        for (int u = 0; u < 4; ++u) {
            float w = act[u] ? __expf(p[u] * 0.25f) : 0.0f;
            acc0 = fmaf(w, (float)v[u].a[0], acc0);
            acc1 = fmaf(w, (float)v[u].a[1], acc1);
            acc2 = fmaf(w, (float)v[u].b[0], acc2);
            acc3 = fmaf(w, (float)v[u].b[1], acc3);
            lsum += w;
        }
    }

    // reduce across the 4 edge-slots (lanes ^16, ^32 hold same features)
    acc0 += __shfl_xor(acc0, 16, 64);  acc0 += __shfl_xor(acc0, 32, 64);
    acc1 += __shfl_xor(acc1, 16, 64);  acc1 += __shfl_xor(acc1, 32, 64);
    acc2 += __shfl_xor(acc2, 16, 64);  acc2 += __shfl_xor(acc2, 32, 64);
    acc3 += __shfl_xor(acc3, 16, 64);  acc3 += __shfl_xor(acc3, 32, 64);
    lsum += __shfl_xor(lsum, 16, 64);  lsum += __shfl_xor(lsum, 32, 64);

    if (lane < 16) {
        float inv = (lsum > 0.0f) ? 1.0f / lsum : 0.0f;
        *(float4*)&out[(size_t)node * HF + 4 * hl] =
            make_float4(acc0 * inv, acc1 * inv, acc2 * inv, acc3 * inv);
    }
}

extern "C" void kernel_launch(void* const* d_in, const int* in_sizes, int n_in,
                              void* d_out, int out_size, void* d_ws, size_t ws_size,
                              hipStream_t stream) {
    const float* feat = (const float*)d_in[0];
    const float* W = (const float*)d_in[1];
    const int* src = (const int*)d_in[2];
    const int* dst = (const int*)d_in[3];
    float* out = (float*)d_out;

    // workspace layout (all 16B-aligned)
    __half* fth = (__half*)d_ws;                             // N*64 halves (6.4 MB)
    int* recs = (int*)(fth + (size_t)N_NODES * HF);          // NBUCKETS*BCAP ints (4.0 MB)
    unsigned short* csr = (unsigned short*)(recs + (size_t)NBUCKETS * BCAP);  // 2.0 MB
    int2* rows = (int2*)(csr + (size_t)NBUCKETS * BCAP);     // N int2 (0.4 MB)
    int* gcur = (int*)(rows + N_NODES);                      // NBUCKETS ints

    hipMemsetAsync(gcur, 0, NBUCKETS * sizeof(int), stream);
    gemm_kernel<<<GEMM_BLOCKS, 256, 0, stream>>>(feat, W, fth);
    bin_kernel<<<NBIN_BLOCKS, 256, 0, stream>>>(src, dst, gcur, recs);
    sort_kernel<<<NBUCKETS, 256, 0, stream>>>(gcur, recs, csr, rows);
    gather_kernel<<<N_NODES * 64 / 256, 256, 0, stream>>>(fth, rows, csr, out);
}